// Round 2
// baseline (356.717 us; speedup 1.0000x reference)
//
#include <hip/hip_runtime.h>

#define B_ 8
#define N_ 256
#define D_ 128
#define E_ 4096

// ---------------- ws layout (bytes) ----------------
// 0      : mask   int32 [B*N]        (8192)
// 8192   : jlist  int32 [B*N]        (8192)
// 16384  : jcnt   int32 [B]          (32)
// 16448  : cnt    float              (4)
// 16512  : s1     f32  [B*D]         (4096)
// 20608  : s2     f32  [B*D]         (4096)
// 24704  : scale  f32  [D]           (512)
// 25216  : shift  f32  [D]           (512)
// 26624  : Wt     f32  [D*D]         (65536)
// 92160  : M      f32  [D*D]         (65536)
// 157696 : Y      f32  [D*D]         (65536)

__global__ __launch_bounds__(256) void k_prep(const void* __restrict__ edges_raw,
                                              const void* __restrict__ mask_raw,
                                              int* __restrict__ mask,
                                              int* __restrict__ jlist,
                                              int* __restrict__ jcnt,
                                              float* __restrict__ cntbuf) {
    __shared__ unsigned char hit[N_];
    __shared__ int wcnt[4], wbase[4], kcs[B_];
    __shared__ int flags[2];   // [0]: mask is u8/bool, [1]: edges are int32
    int tid = threadIdx.x;
    hit[tid] = 0;
    if (tid < 2) flags[tid] = 0;
    __syncthreads();

    // ---- dtype detection (reads stay within the smallest candidate size) ----
    const unsigned char* mb = (const unsigned char*)mask_raw;
    int loc_m = 0;
    for (int idx = tid; idx < B_ * N_; idx += 256)
        if ((idx & 3) && mb[idx]) loc_m = 1;          // nonzero non-LSB byte => u8 data
    if (loc_m) flags[0] = 1;                          // benign race (all write 1)

    const int* e32 = (const int*)edges_raw;
    int loc_e = 0;
    for (int idx = tid; idx < 2 * E_; idx += 256)
        if ((idx & 1) && e32[idx]) loc_e = 1;         // nonzero odd word => int32 data
    if (loc_e) flags[1] = 1;
    __syncthreads();

    int mask_is_u8 = flags[0];
    int e_is_i32 = flags[1];
    const long long* e64 = (const long long*)edges_raw;
    for (int e = tid; e < E_; e += 256) {
        int s, d;
        if (e_is_i32) { s = e32[e]; d = e32[E_ + e]; }
        else          { s = (int)e64[e]; d = (int)e64[E_ + e]; }
        if (d - s == 3) { hit[s] = 1; hit[d] = 1; }
    }
    __syncthreads();

    const int* m32 = (const int*)mask_raw;
    int lane = tid & 63, wid = tid >> 6;
    for (int b = 0; b < B_; ++b) {
        int raw = mask_is_u8 ? (int)(mb[b * N_ + tid] != 0) : (int)(m32[b * N_ + tid] != 0);
        int m = raw && (hit[tid] == 0);
        mask[b * N_ + tid] = m;
        unsigned long long bal = __ballot(m);
        if (lane == 0) wcnt[wid] = __popcll(bal);
        __syncthreads();
        if (tid == 0) {
            int base = 0;
            for (int w = 0; w < 4; ++w) { wbase[w] = base; base += wcnt[w]; }
            jcnt[b] = base; kcs[b] = base;
        }
        __syncthreads();
        if (m) {
            int pos = wbase[wid] + __popcll(bal & ((1ull << lane) - 1ull));
            jlist[b * N_ + pos] = tid;
        }
        __syncthreads();
    }
    if (tid == 0) {
        float c = 0.0f;
        for (int b = 0; b < B_; ++b) { float k = (float)kcs[b]; c += k * k - k; }
        cntbuf[0] = c > 1.0f ? c : 1.0f;
    }
}

// per-batch masked column sums: s1[b,d] = sum_i m*x, s2[b,d] = sum_i m*x^2
__global__ __launch_bounds__(128) void k_colstats(const float* __restrict__ x,
                                                  const int* __restrict__ jlist,
                                                  const int* __restrict__ jcnt,
                                                  float* __restrict__ s1,
                                                  float* __restrict__ s2) {
    int b = blockIdx.x, d = threadIdx.x;
    int kc = jcnt[b];
    float a1 = 0.0f, a2 = 0.0f;
    for (int t = 0; t < kc; ++t) {
        int i = jlist[b * N_ + t];
        float v = x[(b * N_ + i) * D_ + d];
        a1 += v; a2 += v * v;
    }
    s1[b * D_ + d] = a1;
    s2[b * D_ + d] = a2;
}

// M[d,dp] = sum_b ( C_b[d,dp]^2 - Q_b[d,dp] ), C = masked Gram(x), Q = masked Gram(x^2)
__global__ __launch_bounds__(128) void k_gram(const float* __restrict__ x,
                                              const int* __restrict__ jlist,
                                              const int* __restrict__ jcnt,
                                              float* __restrict__ M) {
    int d = blockIdx.x, dp = threadIdx.x;
    float macc = 0.0f;
    for (int b = 0; b < B_; ++b) {
        int kc = jcnt[b];
        float c = 0.0f, q = 0.0f;
#pragma unroll 4
        for (int t = 0; t < kc; ++t) {
            int i = jlist[b * N_ + t];
            const float* row = x + (b * N_ + i) * D_;
            float xd = row[d], xp = row[dp];
            c += xd * xp;
            q += (xd * xd) * (xp * xp);
        }
        macc += c * c - q;
    }
    M[d * D_ + dp] = macc;
}

__global__ __launch_bounds__(128) void k_transpose(const float* __restrict__ W,
                                                   float* __restrict__ Wt) {
    int e = blockIdx.x, d = threadIdx.x;
    Wt[d * D_ + e] = W[e * D_ + d];
}

// Y[d,e] = sum_dp M[d,dp] * W[e,dp]
__global__ __launch_bounds__(128) void k_mw(const float* __restrict__ M,
                                            const float* __restrict__ Wt,
                                            float* __restrict__ Y) {
    int d = blockIdx.x, e = threadIdx.x;
    const float* mrow = M + d * D_;
    float acc = 0.0f;
#pragma unroll 4
    for (int dp = 0; dp < D_; ++dp) acc += mrow[dp] * Wt[dp * D_ + e];
    Y[d * D_ + e] = acc;
}

__global__ __launch_bounds__(128) void k_finalize(const float* __restrict__ s1,
                                                  const float* __restrict__ s2,
                                                  const float* __restrict__ W,
                                                  const float* __restrict__ Wt,
                                                  const float* __restrict__ Y,
                                                  const float* __restrict__ bvec,
                                                  const float* __restrict__ gamma,
                                                  const float* __restrict__ beta,
                                                  const float* __restrict__ cntbuf,
                                                  float* __restrict__ scale,
                                                  float* __restrict__ shift) {
    __shared__ float Ss[D_];
    int e = threadIdx.x;
    float sv = 0.0f;
    for (int b = 0; b < B_; ++b) {
        float v1 = s1[b * D_ + e], v2 = s2[b * D_ + e];
        sv += v1 * v1 - v2;
    }
    Ss[e] = sv;
    __syncthreads();
    float cnt = cntbuf[0];
    const float* wrow = W + e * D_;
    float dot = 0.0f, t = 0.0f;
#pragma unroll 4
    for (int d = 0; d < D_; ++d) {
        dot += wrow[d] * Ss[d];
        t += Wt[d * D_ + e] * Y[d * D_ + e];
    }
    float be = bvec[e];
    float mean = dot / cnt + be;
    float eh2 = t / cnt + 2.0f * be * (mean - be) + be * be;
    float var = eh2 - mean * mean;
    if (var < 0.0f) var = 0.0f;
    float sc = gamma[e] * rsqrtf(var + 1e-5f);
    scale[e] = sc;
    shift[e] = be * sc + beta[e] - mean * sc;
}

// main: per masked (b,i): compute h rows for masked j (compacted), affine+leaky, write.
__global__ __launch_bounds__(256) void k_main(const float* __restrict__ x,
                                              const int* __restrict__ mask,
                                              const int* __restrict__ jlist,
                                              const int* __restrict__ jcnt,
                                              const float* __restrict__ Wt,
                                              const float* __restrict__ scale,
                                              const float* __restrict__ shift,
                                              float* __restrict__ out,
                                              float* __restrict__ pair) {
    int b = blockIdx.y, i = blockIdx.x;
    int tid = threadIdx.x;
    if (!mask[b * N_ + i]) return;   // uniform across block

    // pair_mask row (unmasked i rows stay memset-zero)
    float pm = (mask[b * N_ + tid] && tid != i) ? 1.0f : 0.0f;
    pair[(b * N_ + i) * N_ + tid] = pm;

    __shared__ __align__(16) float xi[D_];
    __shared__ float V[64][129];
    if (tid < D_) xi[tid] = x[(b * N_ + i) * D_ + tid];

    int eg = tid & 15;       // e-group: e0 = eg*8
    int e0 = eg * 8;
    int j0 = (tid >> 4) * 4; // 16 j-groups * 4 = 64

    float sc[8], sh[8];
#pragma unroll
    for (int k = 0; k < 8; ++k) { sc[k] = scale[e0 + k]; sh[k] = shift[e0 + k]; }

    int kc = jcnt[b];
    const float4* x4 = (const float4*)x;
    const float4* Wt4 = (const float4*)Wt;

    for (int jt = 0; jt < kc; jt += 64) {
        __syncthreads();  // xi ready (1st iter) / V no longer in use (later iters)
        int jn = kc - jt; if (jn > 64) jn = 64;
        int c = tid & 31;
        int r0 = tid >> 5;
#pragma unroll
        for (int k = 0; k < 8; ++k) {
            int r = r0 + k * 8;
            float vx0 = 0.f, vx1 = 0.f, vx2 = 0.f, vx3 = 0.f;
            if (r < jn) {
                int j = jlist[b * N_ + jt + r];
                float4 xv = x4[(b * N_ + j) * 32 + c];
                vx0 = xv.x * xi[4 * c + 0];
                vx1 = xv.y * xi[4 * c + 1];
                vx2 = xv.z * xi[4 * c + 2];
                vx3 = xv.w * xi[4 * c + 3];
            }
            V[r][4 * c + 0] = vx0;
            V[r][4 * c + 1] = vx1;
            V[r][4 * c + 2] = vx2;
            V[r][4 * c + 3] = vx3;
        }
        __syncthreads();

        float acc[4][8];
#pragma unroll
        for (int jj = 0; jj < 4; ++jj)
#pragma unroll
            for (int k = 0; k < 8; ++k) acc[jj][k] = 0.0f;

        for (int d = 0; d < D_; ++d) {
            float4 w0 = Wt4[d * 32 + eg * 2];
            float4 w1 = Wt4[d * 32 + eg * 2 + 1];
            float wv[8] = {w0.x, w0.y, w0.z, w0.w, w1.x, w1.y, w1.z, w1.w};
            float av[4] = {V[j0][d], V[j0 + 1][d], V[j0 + 2][d], V[j0 + 3][d]};
#pragma unroll
            for (int jj = 0; jj < 4; ++jj)
#pragma unroll
                for (int k = 0; k < 8; ++k) acc[jj][k] += av[jj] * wv[k];
        }

#pragma unroll
        for (int jj = 0; jj < 4; ++jj) {
            int idx = jt + j0 + jj;
            if (idx < kc) {
                int j = jlist[b * N_ + idx];
                if (j != i) {
                    float tmp[8];
#pragma unroll
                    for (int k = 0; k < 8; ++k) {
                        float v = acc[jj][k] * sc[k] + sh[k];
                        tmp[k] = v >= 0.0f ? v : 0.01f * v;
                    }
                    float4* op = (float4*)(out + (((size_t)(b * N_ + i) * N_ + j) * D_ + e0));
                    op[0] = make_float4(tmp[0], tmp[1], tmp[2], tmp[3]);
                    op[1] = make_float4(tmp[4], tmp[5], tmp[6], tmp[7]);
                }
            }
        }
    }
}

extern "C" void kernel_launch(void* const* d_in, const int* in_sizes, int n_in,
                              void* d_out, int out_size, void* d_ws, size_t ws_size,
                              hipStream_t stream) {
    const float* x = (const float*)d_in[0];
    const void* edges = d_in[1];
    const void* mask_in = d_in[2];
    const float* W = (const float*)d_in[3];
    const float* bvec = (const float*)d_in[4];
    const float* gamma = (const float*)d_in[5];
    const float* beta = (const float*)d_in[6];

    float* out = (float*)d_out;
    float* pair = out + (size_t)B_ * N_ * N_ * D_;

    char* ws = (char*)d_ws;
    int* mask = (int*)(ws + 0);
    int* jlist = (int*)(ws + 8192);
    int* jcnt = (int*)(ws + 16384);
    float* cntbuf = (float*)(ws + 16448);
    float* s1 = (float*)(ws + 16512);
    float* s2 = (float*)(ws + 20608);
    float* scale = (float*)(ws + 24704);
    float* shift = (float*)(ws + 25216);
    float* Wt = (float*)(ws + 26624);
    float* M = (float*)(ws + 92160);
    float* Y = (float*)(ws + 157696);

    hipMemsetAsync(d_out, 0, (size_t)out_size * 4, stream);
    k_prep<<<1, 256, 0, stream>>>(edges, mask_in, mask, jlist, jcnt, cntbuf);
    k_colstats<<<8, 128, 0, stream>>>(x, jlist, jcnt, s1, s2);
    k_gram<<<128, 128, 0, stream>>>(x, jlist, jcnt, M);
    k_transpose<<<128, 128, 0, stream>>>(W, Wt);
    k_mw<<<128, 128, 0, stream>>>(M, Wt, Y);
    k_finalize<<<1, 128, 0, stream>>>(s1, s2, W, Wt, Y, bvec, gamma, beta, cntbuf, scale, shift);
    dim3 grid(N_, B_);
    k_main<<<grid, 256, 0, stream>>>(x, mask, jlist, jcnt, Wt, scale, shift, out, pair);
}

// Round 3
// 120.195 us; speedup vs baseline: 2.9678x; 2.9678x over previous
//
#include <hip/hip_runtime.h>

#define B_ 8
#define N_ 256
#define D_ 128
#define E_ 4096

typedef __attribute__((ext_vector_type(8))) short bf16x8;
typedef __attribute__((ext_vector_type(4))) float f32x4;

__device__ inline unsigned int pack2bf(float lo, float hi) {
    unsigned ul = __float_as_uint(lo);
    ul = ul + 0x7FFFu + ((ul >> 16) & 1u);
    unsigned uh = __float_as_uint(hi);
    uh = uh + 0x7FFFu + ((uh >> 16) & 1u);
    return (ul >> 16) | (uh & 0xFFFF0000u);
}

__device__ inline unsigned short f2bf(float f) {
    unsigned u = __float_as_uint(f);
    u = u + 0x7FFFu + ((u >> 16) & 1u);
    return (unsigned short)(u >> 16);
}

// ---------------- ws layout (bytes) ----------------
// 0      : mask   int32 [B*N]            (8192)
// 8192   : jlist  int32 [B*N]            (8192)
// 16384  : jcnt   int32 [B]              (32)
// 16448  : cnt    float                  (4)
// 16512  : s1     f32  [B*D]             (4096)
// 20608  : s2     f32  [B*D]             (4096)
// 24704  : scale  f32  [D]               (512)
// 25216  : shift  f32  [D]               (512)
// 26624  : Wt     f32  [D][E]            (65536)   (Wt[d*128+e] = W[e][d])
// 92160  : Wb     bf16 [E][D]            (32768)   (row-major W cast to bf16)
// 124928 : Y      f32  [D][E]            (65536)
// 190464 : part   f32  [B][D][D]         (524288)  (per-batch C^2-Q partials)
// total 714752

__global__ __launch_bounds__(256) void k_prep(const void* __restrict__ edges_raw,
                                              const void* __restrict__ mask_raw,
                                              int* __restrict__ mask,
                                              int* __restrict__ jlist,
                                              int* __restrict__ jcnt,
                                              float* __restrict__ cntbuf) {
    __shared__ unsigned char hit[N_];
    __shared__ int wcnt[4], wbase[4], kcs[B_];
    __shared__ int flags[2];   // [0]: mask is u8/bool, [1]: edges are int32
    int tid = threadIdx.x;
    hit[tid] = 0;
    if (tid < 2) flags[tid] = 0;
    __syncthreads();

    const unsigned char* mb = (const unsigned char*)mask_raw;
    int loc_m = 0;
    for (int idx = tid; idx < B_ * N_; idx += 256)
        if ((idx & 3) && mb[idx]) loc_m = 1;
    if (loc_m) flags[0] = 1;

    const int* e32 = (const int*)edges_raw;
    int loc_e = 0;
    for (int idx = tid; idx < 2 * E_; idx += 256)
        if ((idx & 1) && e32[idx]) loc_e = 1;
    if (loc_e) flags[1] = 1;
    __syncthreads();

    int mask_is_u8 = flags[0];
    int e_is_i32 = flags[1];
    const long long* e64 = (const long long*)edges_raw;
    for (int e = tid; e < E_; e += 256) {
        int s, d;
        if (e_is_i32) { s = e32[e]; d = e32[E_ + e]; }
        else          { s = (int)e64[e]; d = (int)e64[E_ + e]; }
        if (d - s == 3) { hit[s] = 1; hit[d] = 1; }
    }
    __syncthreads();

    const int* m32 = (const int*)mask_raw;
    int lane = tid & 63, wid = tid >> 6;
    for (int b = 0; b < B_; ++b) {
        int raw = mask_is_u8 ? (int)(mb[b * N_ + tid] != 0) : (int)(m32[b * N_ + tid] != 0);
        int m = raw && (hit[tid] == 0);
        mask[b * N_ + tid] = m;
        unsigned long long bal = __ballot(m);
        if (lane == 0) wcnt[wid] = __popcll(bal);
        __syncthreads();
        if (tid == 0) {
            int base = 0;
            for (int w = 0; w < 4; ++w) { wbase[w] = base; base += wcnt[w]; }
            jcnt[b] = base; kcs[b] = base;
        }
        __syncthreads();
        if (m) {
            int pos = wbase[wid] + __popcll(bal & ((1ull << lane) - 1ull));
            jlist[b * N_ + pos] = tid;
        }
        __syncthreads();
    }
    if (tid == 0) {
        float c = 0.0f;
        for (int b = 0; b < B_; ++b) { float k = (float)kcs[b]; c += k * k - k; }
        cntbuf[0] = c > 1.0f ? c : 1.0f;
    }
}

// Wt[d][e] = W[e][d] (fp32) ; Wb[e][d] = bf16(W[e][d])
__global__ __launch_bounds__(128) void k_wprep(const float* __restrict__ W,
                                               float* __restrict__ Wt,
                                               unsigned short* __restrict__ Wb) {
    int e = blockIdx.x, d = threadIdx.x;
    float w = W[e * D_ + d];
    Wt[d * D_ + e] = w;
    Wb[e * D_ + d] = f2bf(w);
}

// per (b,d): part[b][d][dp] = C_b[d,dp]^2 - Q_b[d,dp]; also s1[b,d], s2[b,d]
__global__ __launch_bounds__(128) void k_gram2(const float* __restrict__ x,
                                               const int* __restrict__ jlist,
                                               const int* __restrict__ jcnt,
                                               float* __restrict__ part,
                                               float* __restrict__ s1,
                                               float* __restrict__ s2) {
    int d = blockIdx.x, b = blockIdx.y, dp = threadIdx.x;
    int kc = jcnt[b];
    const int* jl = jlist + b * N_;
    float c = 0.0f, q = 0.0f, sa = 0.0f;
#pragma unroll 4
    for (int t = 0; t < kc; ++t) {
        int i = jl[t];
        const float* row = x + (size_t)(b * N_ + i) * D_;
        float xd = row[d], xp = row[dp];
        c += xd * xp;
        q += (xd * xd) * (xp * xp);
        sa += xd;
    }
    part[((size_t)b * D_ + d) * D_ + dp] = c * c - q;
    if (dp == d) s2[b * D_ + d] = c;      // sum of xd^2
    if (dp == 0) s1[b * D_ + d] = sa;     // sum of xd
}

// Y[d][e] = sum_dp (sum_b part[b][d][dp]) * Wt[dp][e]
__global__ __launch_bounds__(128) void k_mw(const float* __restrict__ part,
                                            const float* __restrict__ Wt,
                                            float* __restrict__ Y) {
    __shared__ float Mrow[D_];
    int d = blockIdx.x, e = threadIdx.x;
    float m = 0.0f;
#pragma unroll
    for (int b = 0; b < B_; ++b) m += part[((size_t)b * D_ + d) * D_ + e];
    Mrow[e] = m;
    __syncthreads();
    float acc = 0.0f;
#pragma unroll 8
    for (int dp = 0; dp < D_; ++dp) acc += Mrow[dp] * Wt[dp * D_ + e];
    Y[d * D_ + e] = acc;
}

__global__ __launch_bounds__(128) void k_finalize(const float* __restrict__ s1,
                                                  const float* __restrict__ s2,
                                                  const float* __restrict__ W,
                                                  const float* __restrict__ Wt,
                                                  const float* __restrict__ Y,
                                                  const float* __restrict__ bvec,
                                                  const float* __restrict__ gamma,
                                                  const float* __restrict__ beta,
                                                  const float* __restrict__ cntbuf,
                                                  float* __restrict__ scale,
                                                  float* __restrict__ shift) {
    __shared__ float Ss[D_];
    int e = threadIdx.x;
    float sv = 0.0f;
    for (int b = 0; b < B_; ++b) {
        float v1 = s1[b * D_ + e], v2 = s2[b * D_ + e];
        sv += v1 * v1 - v2;
    }
    Ss[e] = sv;
    __syncthreads();
    float cnt = cntbuf[0];
    const float* wrow = W + e * D_;
    float dot = 0.0f, t = 0.0f;
#pragma unroll 4
    for (int d = 0; d < D_; ++d) {
        dot += wrow[d] * Ss[d];
        t += Wt[d * D_ + e] * Y[d * D_ + e];
    }
    float be = bvec[e];
    float mean = dot / cnt + be;
    float eh2 = t / cnt + 2.0f * be * (mean - be) + be * be;
    float var = eh2 - mean * mean;
    if (var < 0.0f) var = 0.0f;
    float sc = gamma[e] * rsqrtf(var + 1e-5f);
    scale[e] = sc;
    shift[e] = be * sc + beta[e] - mean * sc;
}

// Fused zero-fill + MFMA compute. One block per (b,i).
__global__ __launch_bounds__(256) void k_main(const float* __restrict__ x,
                                              const int* __restrict__ mask,
                                              const int* __restrict__ jlist,
                                              const int* __restrict__ jcnt,
                                              const unsigned short* __restrict__ Wb,
                                              const float* __restrict__ scale,
                                              const float* __restrict__ shift,
                                              float* __restrict__ out,
                                              float* __restrict__ pair) {
    __shared__ int msk[N_];
    __shared__ __align__(16) unsigned char Vsb[64 * 256];  // 64 rows x 128 bf16, XOR-swizzled

    int b = blockIdx.y, i = blockIdx.x;
    int tid = threadIdx.x;
    msk[tid] = mask[b * N_ + tid];
    __syncthreads();
    int mi = msk[i];

    // pair row (always fully written)
    float pm = (mi && msk[tid] && tid != i) ? 1.0f : 0.0f;
    pair[(size_t)(b * N_ + i) * N_ + tid] = pm;

    float4 z4 = make_float4(0.f, 0.f, 0.f, 0.f);
    float4* outrow = (float4*)(out + (size_t)(b * N_ + i) * N_ * D_);

    if (!mi) {   // uniform per block: zero the whole [N][D] slab
        for (int k = tid; k < N_ * D_ / 4; k += 256) outrow[k] = z4;
        return;
    }

    // zero rows not produced below: unmasked j, and j == i
    {
        int c = tid & 31, g = tid >> 5;
        for (int j = g; j < N_; j += 8)
            if (!msk[j] || j == i) outrow[j * 32 + c] = z4;
    }

    int w = tid >> 6, l = tid & 63;
    int lo16 = l & 15, hi4 = l >> 4;      // hi4: 0..3
    int E0 = w * 32;

    // B fragments: Wb[e][d], lane holds B[k][n]: n=lane&15, k=hi4*8+0..7 (+ks*32)
    bf16x8 bfrag[2][4];
#pragma unroll
    for (int et = 0; et < 2; ++et) {
        int e = E0 + et * 16 + lo16;
#pragma unroll
        for (int ks = 0; ks < 4; ++ks)
            bfrag[et][ks] = *(const bf16x8*)(Wb + (size_t)e * D_ + ks * 32 + hi4 * 8);
    }
    float sc0 = scale[E0 + lo16], sh0 = shift[E0 + lo16];
    float sc1 = scale[E0 + 16 + lo16], sh1 = shift[E0 + 16 + lo16];

    int kc = jcnt[b];
    const int* jl = jlist + b * N_;
    const float* xi = x + (size_t)(b * N_ + i) * D_;
    float* outbase = out + (size_t)(b * N_ + i) * N_ * D_;

    for (int jt = 0; jt < kc; jt += 64) {
        __syncthreads();   // Vsb free for restaging
        int jn = kc - jt; if (jn > 64) jn = 64;

        // stage V[r][d] = bf16(x_j[d] * x_i[d]); thread: row r=tid>>2, 32 d's
        {
            int r = tid >> 2, q = tid & 3;
            int jrow = jt + r;
            bool ok = (r < jn);
            const float* xj = ok ? (x + (size_t)(b * N_ + jl[jrow]) * D_) : xi;
            int d0 = q * 32;
#pragma unroll
            for (int c4 = 0; c4 < 4; ++c4) {
                int d = d0 + c4 * 8;
                float4 a0 = *(const float4*)(xj + d);
                float4 a1 = *(const float4*)(xj + d + 4);
                float4 b0 = *(const float4*)(xi + d);
                float4 b1 = *(const float4*)(xi + d + 4);
                uint4 pk;
                pk.x = pack2bf(a0.x * b0.x, a0.y * b0.y);
                pk.y = pack2bf(a0.z * b0.z, a0.w * b0.w);
                pk.z = pack2bf(a1.x * b1.x, a1.y * b1.y);
                pk.w = pack2bf(a1.z * b1.z, a1.w * b1.w);
                if (!ok) pk = make_uint4(0u, 0u, 0u, 0u);
                int byte = r * 256 + ((d * 2) ^ ((r & 7) << 4));
                *(uint4*)(Vsb + byte) = pk;
            }
        }
        __syncthreads();

        // MFMA: per wave, 4 j-subtiles x 2 e-subtiles x 4 k-steps
        f32x4 acc[4][2];
#pragma unroll
        for (int jq = 0; jq < 4; ++jq) {
            acc[jq][0] = (f32x4)(0.f);
            acc[jq][1] = (f32x4)(0.f);
            int rA = jq * 16 + lo16;
            int rbase = rA * 256;
            int rx = (rA & 7) << 4;
            bf16x8 a0 = *(const bf16x8*)(Vsb + rbase + (((hi4 * 8) * 2) ^ rx));
            bf16x8 a1 = *(const bf16x8*)(Vsb + rbase + (((32 + hi4 * 8) * 2) ^ rx));
            bf16x8 a2 = *(const bf16x8*)(Vsb + rbase + (((64 + hi4 * 8) * 2) ^ rx));
            bf16x8 a3 = *(const bf16x8*)(Vsb + rbase + (((96 + hi4 * 8) * 2) ^ rx));
            acc[jq][0] = __builtin_amdgcn_mfma_f32_16x16x32_bf16(a0, bfrag[0][0], acc[jq][0], 0, 0, 0);
            acc[jq][1] = __builtin_amdgcn_mfma_f32_16x16x32_bf16(a0, bfrag[1][0], acc[jq][1], 0, 0, 0);
            acc[jq][0] = __builtin_amdgcn_mfma_f32_16x16x32_bf16(a1, bfrag[0][1], acc[jq][0], 0, 0, 0);
            acc[jq][1] = __builtin_amdgcn_mfma_f32_16x16x32_bf16(a1, bfrag[1][1], acc[jq][1], 0, 0, 0);
            acc[jq][0] = __builtin_amdgcn_mfma_f32_16x16x32_bf16(a2, bfrag[0][2], acc[jq][0], 0, 0, 0);
            acc[jq][1] = __builtin_amdgcn_mfma_f32_16x16x32_bf16(a2, bfrag[1][2], acc[jq][1], 0, 0, 0);
            acc[jq][0] = __builtin_amdgcn_mfma_f32_16x16x32_bf16(a3, bfrag[0][3], acc[jq][0], 0, 0, 0);
            acc[jq][1] = __builtin_amdgcn_mfma_f32_16x16x32_bf16(a3, bfrag[1][3], acc[jq][1], 0, 0, 0);
        }

        // epilogue: D row=(lane>>4)*4+v, col=lane&15
#pragma unroll
        for (int jq = 0; jq < 4; ++jq) {
#pragma unroll
            for (int v = 0; v < 4; ++v) {
                int jrow = jt + jq * 16 + hi4 * 4 + v;
                if (jrow < kc) {
                    int j = jl[jrow];
                    if (j != i) {
                        float* op = outbase + (size_t)j * D_ + E0 + lo16;
                        float h0 = acc[jq][0][v] * sc0 + sh0;
                        float h1 = acc[jq][1][v] * sc1 + sh1;
                        op[0]  = h0 >= 0.f ? h0 : 0.01f * h0;
                        op[16] = h1 >= 0.f ? h1 : 0.01f * h1;
                    }
                }
            }
        }
    }
}

extern "C" void kernel_launch(void* const* d_in, const int* in_sizes, int n_in,
                              void* d_out, int out_size, void* d_ws, size_t ws_size,
                              hipStream_t stream) {
    const float* x = (const float*)d_in[0];
    const void* edges = d_in[1];
    const void* mask_in = d_in[2];
    const float* W = (const float*)d_in[3];
    const float* bvec = (const float*)d_in[4];
    const float* gamma = (const float*)d_in[5];
    const float* beta = (const float*)d_in[6];

    float* out = (float*)d_out;
    float* pair = out + (size_t)B_ * N_ * N_ * D_;

    char* ws = (char*)d_ws;
    int* mask = (int*)(ws + 0);
    int* jlist = (int*)(ws + 8192);
    int* jcnt = (int*)(ws + 16384);
    float* cntbuf = (float*)(ws + 16448);
    float* s1 = (float*)(ws + 16512);
    float* s2 = (float*)(ws + 20608);
    float* scale = (float*)(ws + 24704);
    float* shift = (float*)(ws + 25216);
    float* Wt = (float*)(ws + 26624);
    unsigned short* Wb = (unsigned short*)(ws + 92160);
    float* Y = (float*)(ws + 124928);
    float* part = (float*)(ws + 190464);

    k_prep<<<1, 256, 0, stream>>>(edges, mask_in, mask, jlist, jcnt, cntbuf);
    k_wprep<<<128, 128, 0, stream>>>(W, Wt, Wb);
    {
        dim3 g(D_, B_);
        k_gram2<<<g, 128, 0, stream>>>(x, jlist, jcnt, part, s1, s2);
    }
    k_mw<<<128, 128, 0, stream>>>(part, Wt, Y);
    k_finalize<<<1, 128, 0, stream>>>(s1, s2, W, Wt, Y, bvec, gamma, beta, cntbuf, scale, shift);
    {
        dim3 g(N_, B_);
        k_main<<<g, 256, 0, stream>>>(x, mask, jlist, jcnt, Wb, scale, shift, out, pair);
    }
}